// Round 21
// baseline (46.025 us; speedup 1.0000x reference)
//
#include <hip/hip_runtime.h>
#include <cmath>

namespace {
constexpr int B = 8, N = 1024, IND = 256, OUTD = 256, H = 8, D = 32;
constexpr float LOG2E = 1.4426950408889634f;
}

typedef __attribute__((ext_vector_type(8))) short short8v;
typedef __attribute__((ext_vector_type(4))) float f32x4;

union pk8_t {
  uint u[4];
  short8v s;
};

__device__ inline uint cvt_pk(float lo, float hi) {
  uint r;
  asm("v_cvt_pk_bf16_f32 %0, %1, %2" : "=v"(r) : "v"(lo), "v"(hi));
  return r;
}
__device__ inline float lo16f(uint u) { return __uint_as_float(u << 16); }
__device__ inline float hi16f(uint u) { return __uint_as_float(u & 0xFFFF0000u); }

// ---------------------------------------------------------------------------
// K1: heterogeneous {GEMM || bitpack}, 2304 blocks.
//  bid < 256: GEMM, 64 rows x 128 cols (4 heads) per block — x re-read 2x
//    instead of 4x (was 64x64). ct loop 4->8, W staging 16KB, acc[8].
//  bid >= 256: bitpack (byte-identical to r20, offset shifted).
// ---------------------------------------------------------------------------
__global__ __launch_bounds__(256) void gat_k1(
    const float* __restrict__ x, const float* __restrict__ W,
    const float* __restrict__ a, const int* __restrict__ adj,
    uint* __restrict__ bitsT, float* __restrict__ siT,
    float* __restrict__ sjT, ushort* __restrict__ hTbF) {
  const int bid = blockIdx.x;
  const int t = threadIdx.x;

  if (bid >= 256) {
    // ---- bitpack ----
    const int lane = t & 63, w = t >> 6;
    const int wid = (bid - 256) * 4 + w;  // 0..8191 = b*N + i
    const int b = wid >> 10, i = wid & 1023;
    const int4* ap = (const int4*)(adj + ((size_t)b * N + i) * N);
#pragma unroll
    for (int c = 0; c < 4; ++c) {
      const int4 v = ap[c * 64 + lane];
      uint val = (v.x != 0 ? 1u : 0u) | (v.y != 0 ? 2u : 0u) |
                 (v.z != 0 ? 4u : 0u) | (v.w != 0 ? 8u : 0u);
      val <<= (lane & 7) * 4;
      val |= (uint)__shfl_xor((int)val, 1);
      val |= (uint)__shfl_xor((int)val, 2);
      val |= (uint)__shfl_xor((int)val, 4);
      if ((lane & 7) == 0) {
        const int jt = c * 8 + (lane >> 3);
        bitsT[((size_t)b * 32 + jt) * N + i] = val;
      }
    }
    return;
  }

  // ---- GEMM ----
  __shared__ __align__(16) char smem[33280];
  float(*xs)[36] = (float(*)[36])smem;      // 64 x 36 f32 (9216 B)
  ushort* wsh = (ushort*)(smem + 9216);     // 4096 ushort (8 KB)
  ushort* wsl = (ushort*)(smem + 17408);    // 4096 ushort (8 KB)
  float(*tile2)[130] = (float(*)[130])smem; // post-loop alias (33280 B)

  const int lane = t & 63, w = t >> 6;
  const int la = lane & 15, g = lane >> 4;
  const int work = ((bid & 7) << 5) + (bid >> 3);  // XCD swizzle (256 = 8*32)
  const int bx = work >> 1, cy = work & 1;  // 64-row tile, 128-col half

  f32x4 z = {0.f, 0.f, 0.f, 0.f};
  f32x4 acc[8] = {z, z, z, z, z, z, z, z};

  const float* xp = x + (size_t)(bx * 64 + (t >> 2)) * IND + (t & 3) * 8;
  // W staging coords: thread t -> (l = t&63, ctb = t>>6); 2 ct per thread
  const int l_ = t & 63, ctb = t >> 6;
  const int wc = l_ & 15;
  const int wk0 = ((l_ >> 4) & 3) * 8;

  for (int kb = 0; kb < 8; ++kb) {
    __syncthreads();
    {
      float4 v0 = *(const float4*)(xp + kb * 32);
      float4 v1 = *(const float4*)(xp + kb * 32 + 4);
      float* dst = &xs[t >> 2][(t & 3) * 8];
      *(float4*)dst = v0;
      *(float4*)(dst + 4) = v1;
    }
#pragma unroll
    for (int cc = 0; cc < 2; ++cc) {
      const int ct = ctb * 2 + cc;
      const int c = cy * 128 + ct * 16 + wc;
      const float* wp = W + (size_t)c * IND + kb * 32 + wk0;
      float4 v0 = *(const float4*)(wp);
      float4 v1 = *(const float4*)(wp + 4);
      const float wf[8] = {v0.x, v0.y, v0.z, v0.w, v1.x, v1.y, v1.z, v1.w};
      pk8_t ph_, pl_;
#pragma unroll
      for (int p = 0; p < 4; ++p) {
        const uint hu = cvt_pk(wf[2 * p], wf[2 * p + 1]);
        ph_.u[p] = hu;
        pl_.u[p] = cvt_pk(wf[2 * p] - lo16f(hu), wf[2 * p + 1] - hi16f(hu));
      }
      *(short8v*)&wsh[ct * 512 + l_ * 8] = ph_.s;
      *(short8v*)&wsl[ct * 512 + l_ * 8] = pl_.s;
    }
    __syncthreads();

    const float* xr = &xs[w * 16 + la][g * 8];
    float4 u0 = *(const float4*)(xr);
    float4 u1 = *(const float4*)(xr + 4);
    const float af[8] = {u0.x, u0.y, u0.z, u0.w, u1.x, u1.y, u1.z, u1.w};
    short8v ah, al;
    {
      pk8_t ph_, pl_;
#pragma unroll
      for (int p = 0; p < 4; ++p) {
        const uint hu = cvt_pk(af[2 * p], af[2 * p + 1]);
        ph_.u[p] = hu;
        pl_.u[p] = cvt_pk(af[2 * p] - lo16f(hu), af[2 * p + 1] - hi16f(hu));
      }
      ah = ph_.s;
      al = pl_.s;
    }
#pragma unroll
    for (int ct = 0; ct < 8; ++ct) {
      const short8v bh = *(const short8v*)&wsh[ct * 512 + lane * 8];
      const short8v bl = *(const short8v*)&wsl[ct * 512 + lane * 8];
      acc[ct] = __builtin_amdgcn_mfma_f32_16x16x32_bf16(ah, bh, acc[ct], 0, 0, 0);
      acc[ct] = __builtin_amdgcn_mfma_f32_16x16x32_bf16(al, bh, acc[ct], 0, 0, 0);
      acc[ct] = __builtin_amdgcn_mfma_f32_16x16x32_bf16(ah, bl, acc[ct], 0, 0, 0);
    }
  }

  const int batch = bx >> 4;
  const int nbase = (bx & 15) * 64 + w * 16;

#pragma unroll
  for (int hp2 = 0; hp2 < 4; ++hp2) {
    const int head = cy * 4 + hp2;
    const float a0 = a[head * 64 + la] * LOG2E;
    const float a1 = a[head * 64 + 16 + la] * LOG2E;
    const float a2 = a[head * 64 + 32 + la] * LOG2E;
    const float a3 = a[head * 64 + 48 + la] * LOG2E;
    float s1v[4], s2v[4];
#pragma unroll
    for (int q = 0; q < 4; ++q) {
      s1v[q] = acc[hp2 * 2][q] * a0 + acc[hp2 * 2 + 1][q] * a1;
      s2v[q] = acc[hp2 * 2][q] * a2 + acc[hp2 * 2 + 1][q] * a3;
    }
#pragma unroll
    for (int mask = 1; mask <= 8; mask <<= 1)
#pragma unroll
      for (int q = 0; q < 4; ++q) {
        s1v[q] += __shfl_xor(s1v[q], mask);
        s2v[q] += __shfl_xor(s2v[q], mask);
      }
    if (la == 0) {
#pragma unroll
      for (int q = 0; q < 4; ++q) {
        const size_t o = (size_t)(batch * H + head) * N + nbase + g * 4 + q;
        siT[o] = s1v[q];
        sjT[o] = s2v[q];
      }
    }
  }

  __syncthreads();
#pragma unroll
  for (int ct = 0; ct < 8; ++ct)
#pragma unroll
    for (int q = 0; q < 4; ++q)
      tile2[w * 16 + g * 4 + q][ct * 16 + la] = acc[ct][q];
  __syncthreads();

  const int jt0 = (bx & 15) * 2;
  {
    const int jt_loc = t >> 7, half = (t >> 6) & 1, l = t & 63;
    const int d = half * 16 + (l & 15);
#pragma unroll
    for (int s = 0; s < 4; ++s) {  // head within this 128-col half
      pk8_t pk_;
#pragma unroll
      for (int p = 0; p < 4; ++p)
        pk_.u[p] = cvt_pk(tile2[jt_loc * 32 + (l >> 4) * 8 + 2 * p][s * 32 + d],
                          tile2[jt_loc * 32 + (l >> 4) * 8 + 2 * p + 1][s * 32 + d]);
      const int bh_g = batch * H + cy * 4 + s;
      *(short8v*)(hTbF + ((size_t)(bh_g * 32 + jt0 + jt_loc) * 64 + l) * 16 + half * 8) = pk_.s;
    }
  }
}

// ---------------------------------------------------------------------------
// K2: MFMA aggregation, r14/r20 verbatim (proven passing).
// ---------------------------------------------------------------------------
__global__ __launch_bounds__(256) void gat_agg(
    const uint* __restrict__ bitsT, const float* __restrict__ siT,
    const float* __restrict__ sjT, const ushort* __restrict__ hTbF,
    float* __restrict__ out) {
  __shared__ float sj_lds[1024];      // 4 KB
  __shared__ uint bits_lds[32][32];   // 4 KB
  __shared__ float part[2][64][13];   // partial-combine
  const int t = threadIdx.x;
  const int lane = t & 63, w = t >> 6;
  const int iw = w & 1, jq = w >> 1;
  const int bid = blockIdx.x;
  const int work = ((bid & 7) << 8) + (bid >> 3);  // XCD swizzle (2048 = 8*256)
  const int bh = work >> 5;
  const int itg = work & 31;
  const int b = bh >> 3, hh = bh & 7;
  const int i0 = itg * 32 + iw * 16;
  const int la = lane & 15, g = lane >> 4;
  const int iA = i0 + la;

  const float si_r = siT[(size_t)bh * N + iA];

  // stage sj (full bh row, 4KB) + bits (32 jt x 32 i-local, 4KB)
  {
    float4 v = *(const float4*)(sjT + (size_t)bh * N + t * 4);
    *(float4*)&sj_lds[t * 4] = v;
    const int jt = t >> 3, c4 = (t & 7) * 4;
    uint4 bv = *(const uint4*)(bitsT + ((size_t)b * 32 + jt) * N + itg * 32 + c4);
    *(uint4*)&bits_lds[jt][c4] = bv;
  }
  __syncthreads();

  const ushort* hp = hTbF + (size_t)bh * 32768 + (size_t)jq * 16384 + lane * 16;
  const uint* blp = &bits_lds[jq * 16][iw * 16 + la];  // + jt*32 words
  const float* slp = &sj_lds[jq * 512 + g * 8];        // + jt*32 floats

  f32x4 acc0 = {0.f, 0.f, 0.f, 0.f}, acc1 = {0.f, 0.f, 0.f, 0.f};
  f32x4 accl = {0.f, 0.f, 0.f, 0.f};
  short8v ones;
#pragma unroll
  for (int e = 0; e < 8; ++e) ones[e] = (short)0x3F80;  // bf16(1.0)

  uint bits_A, bits_B;
  float4 sj0A, sj1A, sj0B, sj1B;
  short8v h0A, h1A, h0B, h1B;

#define AGG_LDS(S, JT)                                     \
  bits_##S = blp[(JT)*32];                                 \
  sj0##S = *(const float4*)(slp + (JT) * 32);              \
  sj1##S = *(const float4*)(slp + (JT) * 32 + 4);

#define AGG_LOAD_H(S, JT)                                  \
  h0##S = *(const short8v*)(hp + (size_t)(JT)*1024);       \
  h1##S = *(const short8v*)(hp + (size_t)(JT)*1024 + 8);

#define AGG_COMP(S)                                                           \
  {                                                                           \
    const uint byte_ = (bits_##S >> (g * 8)) & 0xffu;                         \
    const float sjv[8] = {sj0##S.x, sj0##S.y, sj0##S.z, sj0##S.w,             \
                          sj1##S.x, sj1##S.y, sj1##S.z, sj1##S.w};            \
    float wv[8];                                                              \
    _Pragma("unroll") for (int e = 0; e < 8; ++e) {                           \
      float s = si_r + sjv[e];                                                \
      s = fmaxf(s, 0.2f * s);                                                 \
      s = ((byte_ >> e) & 1u) ? s : -INFINITY;                                \
      wv[e] = __builtin_amdgcn_exp2f(s);                                      \
    }                                                                         \
    pk8_t pk_;                                                                \
    pk_.u[0] = cvt_pk(wv[0], wv[1]);                                          \
    pk_.u[1] = cvt_pk(wv[2], wv[3]);                                          \
    pk_.u[2] = cvt_pk(wv[4], wv[5]);                                          \
    pk_.u[3] = cvt_pk(wv[6], wv[7]);                                          \
    const short8v af = pk_.s;                                                 \
    __builtin_amdgcn_s_setprio(1);                                            \
    acc0 = __builtin_amdgcn_mfma_f32_16x16x32_bf16(af, h0##S, acc0, 0, 0, 0); \
    acc1 = __builtin_amdgcn_mfma_f32_16x16x32_bf16(af, h1##S, acc1, 0, 0, 0); \
    accl = __builtin_amdgcn_mfma_f32_16x16x32_bf16(af, ones, accl, 0, 0, 0);  \
    __builtin_amdgcn_s_setprio(0);                                            \
  }

  AGG_LDS(A, 0)
  AGG_LOAD_H(A, 0)
  AGG_LDS(B, 1)
  AGG_LOAD_H(B, 1)
#pragma unroll
  for (int jt = 0; jt < 16; jt += 2) {
    AGG_COMP(A)
    if (jt + 2 < 16) { AGG_LDS(A, jt + 2) AGG_LOAD_H(A, jt + 2) }
    AGG_COMP(B)
    if (jt + 3 < 16) { AGG_LDS(B, jt + 3) AGG_LOAD_H(B, jt + 3) }
  }
#undef AGG_LDS
#undef AGG_LOAD_H
#undef AGG_COMP

  // combine j-halves: jq=1 stores partials, jq=0 adds + epilogue
  if (jq == 1) {
    float* p = part[iw][lane];
#pragma unroll
    for (int k = 0; k < 4; ++k) {
      p[k] = acc0[k];
      p[4 + k] = acc1[k];
      p[8 + k] = accl[k];
    }
  }
  __syncthreads();
  if (jq == 0) {
    const float* p = part[iw][lane];
#pragma unroll
    for (int k = 0; k < 4; ++k) {
      acc0[k] += p[k];
      acc1[k] += p[4 + k];
      accl[k] += p[8 + k];
    }
    float* op = out + ((size_t)(b * N + i0)) * OUTD + hh * D;
#pragma unroll
    for (int r = 0; r < 4; ++r) {
      const int ic = g * 4 + r;
      const float li = accl[r];  // row-sum (identical across cols)
      float v0 = acc0[r] / li;
      v0 = v0 > 0.f ? v0 : expm1f(v0);
      op[(size_t)ic * OUTD + la] = v0;
      float v1 = acc1[r] / li;
      v1 = v1 > 0.f ? v1 : expm1f(v1);
      op[(size_t)ic * OUTD + 16 + la] = v1;
    }
  }
}

extern "C" void kernel_launch(void* const* d_in, const int* in_sizes, int n_in,
                              void* d_out, int out_size, void* d_ws, size_t ws_size,
                              hipStream_t stream) {
  const float* x = (const float*)d_in[0];
  const int* adj = (const int*)d_in[1];
  const float* W = (const float*)d_in[2];
  const float* a = (const float*)d_in[3];
  float* out = (float*)d_out;

  float* ws = (float*)d_ws;
  float* siT = ws;                                   // 65,536 f32
  float* sjT = siT + (size_t)B * N * H;              // 65,536 f32
  uint* bitsT = (uint*)(sjT + (size_t)B * N * H);    // 262,144 u32 (1 MB)
  ushort* hTbF = (ushort*)(bitsT + (size_t)B * 32 * N);  // 2,097,152 bf16 (4 MB)

  gat_k1<<<256 + 2048, 256, 0, stream>>>(x, W, a, adj, bitsT, siT, sjT, hTbF);
  gat_agg<<<2048, 256, 0, stream>>>(bitsT, siT, sjT, hTbF, out);
}

// Round 22
// 41.162 us; speedup vs baseline: 1.1182x; 1.1182x over previous
//
#include <hip/hip_runtime.h>
#include <cmath>

namespace {
constexpr int B = 8, N = 1024, IND = 256, OUTD = 256, H = 8, D = 32;
constexpr float LOG2E = 1.4426950408889634f;
}

typedef __attribute__((ext_vector_type(8))) short short8v;
typedef __attribute__((ext_vector_type(4))) float f32x4;

union pk8_t {
  uint u[4];
  short8v s;
};

__device__ inline uint cvt_pk(float lo, float hi) {
  uint r;
  asm("v_cvt_pk_bf16_f32 %0, %1, %2" : "=v"(r) : "v"(lo), "v"(hi));
  return r;
}
__device__ inline float lo16f(uint u) { return __uint_as_float(u << 16); }
__device__ inline float hi16f(uint u) { return __uint_as_float(u & 0xFFFF0000u); }

// ---------------------------------------------------------------------------
// K1: heterogeneous {GEMM || bitpack}, 2560 blocks. (r20 verbatim — proven)
// ---------------------------------------------------------------------------
__global__ __launch_bounds__(256) void gat_k1(
    const float* __restrict__ x, const float* __restrict__ W,
    const float* __restrict__ a, const int* __restrict__ adj,
    uint* __restrict__ bitsT, float* __restrict__ siT,
    float* __restrict__ sjT, ushort* __restrict__ hTbF) {
  const int bid = blockIdx.x;
  const int t = threadIdx.x;

  if (bid >= 512) {
    // ---- bitpack ----
    const int lane = t & 63, w = t >> 6;
    const int wid = (bid - 512) * 4 + w;  // 0..8191 = b*N + i
    const int b = wid >> 10, i = wid & 1023;
    const int4* ap = (const int4*)(adj + ((size_t)b * N + i) * N);
#pragma unroll
    for (int c = 0; c < 4; ++c) {
      const int4 v = ap[c * 64 + lane];
      uint val = (v.x != 0 ? 1u : 0u) | (v.y != 0 ? 2u : 0u) |
                 (v.z != 0 ? 4u : 0u) | (v.w != 0 ? 8u : 0u);
      val <<= (lane & 7) * 4;
      val |= (uint)__shfl_xor((int)val, 1);
      val |= (uint)__shfl_xor((int)val, 2);
      val |= (uint)__shfl_xor((int)val, 4);
      if ((lane & 7) == 0) {
        const int jt = c * 8 + (lane >> 3);
        bitsT[((size_t)b * 32 + jt) * N + i] = val;
      }
    }
    return;
  }

  // ---- GEMM ----
  __shared__ __align__(16) char smem[17664];
  float(*xs)[36] = (float(*)[36])smem;     // 64 x 36 f32 (9216 B)
  ushort* wsh = (ushort*)(smem + 9216);    // 2048 ushort (4 KB)
  ushort* wsl = (ushort*)(smem + 13312);   // 2048 ushort (4 KB)
  float(*tile2)[65] = (float(*)[65])smem;  // post-loop alias (16640 B)

  const int lane = t & 63, w = t >> 6;
  const int la = lane & 15, g = lane >> 4;
  const int work = ((bid & 7) << 6) + (bid >> 3);  // XCD swizzle (512 = 8*64)
  const int bx = work >> 2, by = work & 3;

  f32x4 z = {0.f, 0.f, 0.f, 0.f};
  f32x4 acc[4] = {z, z, z, z};

  const float* xp = x + (size_t)(bx * 64 + (t >> 2)) * IND + (t & 3) * 8;
  const int w_c = by * 64 + (t >> 6) * 16 + (t & 15);
  const int w_k0 = ((t >> 4) & 3) * 8;
  const float* wp = W + (size_t)w_c * IND + w_k0;

  for (int kb = 0; kb < 8; ++kb) {
    __syncthreads();
    {
      float4 v0 = *(const float4*)(xp + kb * 32);
      float4 v1 = *(const float4*)(xp + kb * 32 + 4);
      float* dst = &xs[t >> 2][(t & 3) * 8];
      *(float4*)dst = v0;
      *(float4*)(dst + 4) = v1;
    }
    {
      float4 v0 = *(const float4*)(wp + kb * 32);
      float4 v1 = *(const float4*)(wp + kb * 32 + 4);
      const float wf[8] = {v0.x, v0.y, v0.z, v0.w, v1.x, v1.y, v1.z, v1.w};
      pk8_t ph_, pl_;
#pragma unroll
      for (int p = 0; p < 4; ++p) {
        const uint hu = cvt_pk(wf[2 * p], wf[2 * p + 1]);
        ph_.u[p] = hu;
        pl_.u[p] = cvt_pk(wf[2 * p] - lo16f(hu), wf[2 * p + 1] - hi16f(hu));
      }
      *(short8v*)&wsh[t * 8] = ph_.s;
      *(short8v*)&wsl[t * 8] = pl_.s;
    }
    __syncthreads();

    const float* xr = &xs[w * 16 + la][g * 8];
    float4 u0 = *(const float4*)(xr);
    float4 u1 = *(const float4*)(xr + 4);
    const float af[8] = {u0.x, u0.y, u0.z, u0.w, u1.x, u1.y, u1.z, u1.w};
    short8v ah, al;
    {
      pk8_t ph_, pl_;
#pragma unroll
      for (int p = 0; p < 4; ++p) {
        const uint hu = cvt_pk(af[2 * p], af[2 * p + 1]);
        ph_.u[p] = hu;
        pl_.u[p] = cvt_pk(af[2 * p] - lo16f(hu), af[2 * p + 1] - hi16f(hu));
      }
      ah = ph_.s;
      al = pl_.s;
    }
#pragma unroll
    for (int ct = 0; ct < 4; ++ct) {
      const short8v bh = *(const short8v*)&wsh[ct * 512 + lane * 8];
      const short8v bl = *(const short8v*)&wsl[ct * 512 + lane * 8];
      acc[ct] = __builtin_amdgcn_mfma_f32_16x16x32_bf16(ah, bh, acc[ct], 0, 0, 0);
      acc[ct] = __builtin_amdgcn_mfma_f32_16x16x32_bf16(al, bh, acc[ct], 0, 0, 0);
      acc[ct] = __builtin_amdgcn_mfma_f32_16x16x32_bf16(ah, bl, acc[ct], 0, 0, 0);
    }
  }

  const int batch = bx >> 4;
  const int nbase = (bx & 15) * 64 + w * 16;

#pragma unroll
  for (int hp2 = 0; hp2 < 2; ++hp2) {
    const int head = by * 2 + hp2;
    const float a0 = a[head * 64 + la] * LOG2E;
    const float a1 = a[head * 64 + 16 + la] * LOG2E;
    const float a2 = a[head * 64 + 32 + la] * LOG2E;
    const float a3 = a[head * 64 + 48 + la] * LOG2E;
    float s1v[4], s2v[4];
#pragma unroll
    for (int q = 0; q < 4; ++q) {
      s1v[q] = acc[hp2 * 2][q] * a0 + acc[hp2 * 2 + 1][q] * a1;
      s2v[q] = acc[hp2 * 2][q] * a2 + acc[hp2 * 2 + 1][q] * a3;
    }
#pragma unroll
    for (int mask = 1; mask <= 8; mask <<= 1)
#pragma unroll
      for (int q = 0; q < 4; ++q) {
        s1v[q] += __shfl_xor(s1v[q], mask);
        s2v[q] += __shfl_xor(s2v[q], mask);
      }
    if (la == 0) {
#pragma unroll
      for (int q = 0; q < 4; ++q) {
        const size_t o = (size_t)(batch * H + head) * N + nbase + g * 4 + q;
        siT[o] = s1v[q];
        sjT[o] = s2v[q];
      }
    }
  }

  __syncthreads();
#pragma unroll
  for (int ct = 0; ct < 4; ++ct)
#pragma unroll
    for (int q = 0; q < 4; ++q)
      tile2[w * 16 + g * 4 + q][ct * 16 + la] = acc[ct][q];
  __syncthreads();

  const int jt0 = (bx & 15) * 2;
#pragma unroll
  for (int s = 0; s < 2; ++s) {
    const int gg = t * 2 + s;  // 0..511
    const int head = gg >> 8, rem = gg & 255;
    const int jt_loc = rem >> 7, half = (rem >> 6) & 1, l = rem & 63;
    const int d = half * 16 + (l & 15);
    pk8_t pk_;
#pragma unroll
    for (int p = 0; p < 4; ++p)
      pk_.u[p] = cvt_pk(tile2[jt_loc * 32 + (l >> 4) * 8 + 2 * p][head * 32 + d],
                        tile2[jt_loc * 32 + (l >> 4) * 8 + 2 * p + 1][head * 32 + d]);
    const int bh_g = batch * H + by * 2 + head;
    *(short8v*)(hTbF + ((size_t)(bh_g * 32 + jt0 + jt_loc) * 64 + l) * 16 + half * 8) = pk_.s;
  }
}

// ---------------------------------------------------------------------------
// K2: MFMA aggregation, r20 verbatim (proven passing).
// ---------------------------------------------------------------------------
__global__ __launch_bounds__(256) void gat_agg(
    const uint* __restrict__ bitsT, const float* __restrict__ siT,
    const float* __restrict__ sjT, const ushort* __restrict__ hTbF,
    float* __restrict__ out) {
  __shared__ float sj_lds[1024];      // 4 KB
  __shared__ uint bits_lds[32][32];   // 4 KB
  __shared__ float part[2][64][13];   // partial-combine
  const int t = threadIdx.x;
  const int lane = t & 63, w = t >> 6;
  const int iw = w & 1, jq = w >> 1;
  const int bid = blockIdx.x;
  const int work = ((bid & 7) << 8) + (bid >> 3);  // XCD swizzle (2048 = 8*256)
  const int bh = work >> 5;
  const int itg = work & 31;
  const int b = bh >> 3, hh = bh & 7;
  const int i0 = itg * 32 + iw * 16;
  const int la = lane & 15, g = lane >> 4;
  const int iA = i0 + la;

  const float si_r = siT[(size_t)bh * N + iA];

  // stage sj (full bh row, 4KB) + bits (32 jt x 32 i-local, 4KB)
  {
    float4 v = *(const float4*)(sjT + (size_t)bh * N + t * 4);
    *(float4*)&sj_lds[t * 4] = v;
    const int jt = t >> 3, c4 = (t & 7) * 4;
    uint4 bv = *(const uint4*)(bitsT + ((size_t)b * 32 + jt) * N + itg * 32 + c4);
    *(uint4*)&bits_lds[jt][c4] = bv;
  }
  __syncthreads();

  const ushort* hp = hTbF + (size_t)bh * 32768 + (size_t)jq * 16384 + lane * 16;
  const uint* blp = &bits_lds[jq * 16][iw * 16 + la];  // + jt*32 words
  const float* slp = &sj_lds[jq * 512 + g * 8];        // + jt*32 floats

  f32x4 acc0 = {0.f, 0.f, 0.f, 0.f}, acc1 = {0.f, 0.f, 0.f, 0.f};
  f32x4 accl = {0.f, 0.f, 0.f, 0.f};
  short8v ones;
#pragma unroll
  for (int e = 0; e < 8; ++e) ones[e] = (short)0x3F80;  // bf16(1.0)

  uint bits_A, bits_B;
  float4 sj0A, sj1A, sj0B, sj1B;
  short8v h0A, h1A, h0B, h1B;

#define AGG_LDS(S, JT)                                     \
  bits_##S = blp[(JT)*32];                                 \
  sj0##S = *(const float4*)(slp + (JT) * 32);              \
  sj1##S = *(const float4*)(slp + (JT) * 32 + 4);

#define AGG_LOAD_H(S, JT)                                  \
  h0##S = *(const short8v*)(hp + (size_t)(JT)*1024);       \
  h1##S = *(const short8v*)(hp + (size_t)(JT)*1024 + 8);

#define AGG_COMP(S)                                                           \
  {                                                                           \
    const uint byte_ = (bits_##S >> (g * 8)) & 0xffu;                         \
    const float sjv[8] = {sj0##S.x, sj0##S.y, sj0##S.z, sj0##S.w,             \
                          sj1##S.x, sj1##S.y, sj1##S.z, sj1##S.w};            \
    float wv[8];                                                              \
    _Pragma("unroll") for (int e = 0; e < 8; ++e) {                           \
      float s = si_r + sjv[e];                                                \
      s = fmaxf(s, 0.2f * s);                                                 \
      s = ((byte_ >> e) & 1u) ? s : -INFINITY;                                \
      wv[e] = __builtin_amdgcn_exp2f(s);                                      \
    }                                                                         \
    pk8_t pk_;                                                                \
    pk_.u[0] = cvt_pk(wv[0], wv[1]);                                          \
    pk_.u[1] = cvt_pk(wv[2], wv[3]);                                          \
    pk_.u[2] = cvt_pk(wv[4], wv[5]);                                          \
    pk_.u[3] = cvt_pk(wv[6], wv[7]);                                          \
    const short8v af = pk_.s;                                                 \
    __builtin_amdgcn_s_setprio(1);                                            \
    acc0 = __builtin_amdgcn_mfma_f32_16x16x32_bf16(af, h0##S, acc0, 0, 0, 0); \
    acc1 = __builtin_amdgcn_mfma_f32_16x16x32_bf16(af, h1##S, acc1, 0, 0, 0); \
    accl = __builtin_amdgcn_mfma_f32_16x16x32_bf16(af, ones, accl, 0, 0, 0);  \
    __builtin_amdgcn_s_setprio(0);                                            \
  }

  AGG_LDS(A, 0)
  AGG_LOAD_H(A, 0)
  AGG_LDS(B, 1)
  AGG_LOAD_H(B, 1)
#pragma unroll
  for (int jt = 0; jt < 16; jt += 2) {
    AGG_COMP(A)
    if (jt + 2 < 16) { AGG_LDS(A, jt + 2) AGG_LOAD_H(A, jt + 2) }
    AGG_COMP(B)
    if (jt + 3 < 16) { AGG_LDS(B, jt + 3) AGG_LOAD_H(B, jt + 3) }
  }
#undef AGG_LDS
#undef AGG_LOAD_H
#undef AGG_COMP

  // combine j-halves: jq=1 stores partials, jq=0 adds + epilogue
  if (jq == 1) {
    float* p = part[iw][lane];
#pragma unroll
    for (int k = 0; k < 4; ++k) {
      p[k] = acc0[k];
      p[4 + k] = acc1[k];
      p[8 + k] = accl[k];
    }
  }
  __syncthreads();
  if (jq == 0) {
    const float* p = part[iw][lane];
#pragma unroll
    for (int k = 0; k < 4; ++k) {
      acc0[k] += p[k];
      acc1[k] += p[4 + k];
      accl[k] += p[8 + k];
    }
    float* op = out + ((size_t)(b * N + i0)) * OUTD + hh * D;
#pragma unroll
    for (int r = 0; r < 4; ++r) {
      const int ic = g * 4 + r;
      const float li = accl[r];  // row-sum (identical across cols)
      float v0 = acc0[r] / li;
      v0 = v0 > 0.f ? v0 : expm1f(v0);
      op[(size_t)ic * OUTD + la] = v0;
      float v1 = acc1[r] / li;
      v1 = v1 > 0.f ? v1 : expm1f(v1);
      op[(size_t)ic * OUTD + 16 + la] = v1;
    }
  }
}

extern "C" void kernel_launch(void* const* d_in, const int* in_sizes, int n_in,
                              void* d_out, int out_size, void* d_ws, size_t ws_size,
                              hipStream_t stream) {
  const float* x = (const float*)d_in[0];
  const int* adj = (const int*)d_in[1];
  const float* W = (const float*)d_in[2];
  const float* a = (const float*)d_in[3];
  float* out = (float*)d_out;

  float* ws = (float*)d_ws;
  float* siT = ws;                                   // 65,536 f32
  float* sjT = siT + (size_t)B * N * H;              // 65,536 f32
  uint* bitsT = (uint*)(sjT + (size_t)B * N * H);    // 262,144 u32 (1 MB)
  ushort* hTbF = (ushort*)(bitsT + (size_t)B * 32 * N);  // 2,097,152 bf16 (4 MB)

  gat_k1<<<512 + 2048, 256, 0, stream>>>(x, W, a, adj, bitsT, siT, sjT, hTbF);
  gat_agg<<<2048, 256, 0, stream>>>(bitsT, siT, sjT, hTbF, out);
}